// Round 1
// baseline (372.124 us; speedup 1.0000x reference)
//
#include <hip/hip_runtime.h>
#include <hip/hip_bf16.h>

#define BB 8
#define NN 2048
#define MM 2048
#define DD 512

typedef __attribute__((ext_vector_type(8))) short bf16x8;
typedef __attribute__((ext_vector_type(4))) float f32x4;
typedef __attribute__((ext_vector_type(8))) unsigned short u16x8;

__device__ __forceinline__ unsigned short f2bf(float x){
  unsigned int u = __float_as_uint(x);
  u += 0x7fffu + ((u>>16)&1u);   // round-to-nearest-even
  return (unsigned short)(u>>16);
}
__device__ __forceinline__ float bf2f(unsigned short h){
  return __uint_as_float(((unsigned int)h)<<16);
}
__device__ __forceinline__ f32x4 mfma16(bf16x8 a, bf16x8 b, f32x4 c){
  return __builtin_amdgcn_mfma_f32_16x16x32_bf16(a, b, c, 0, 0, 0);
}

// ---------------------------------------------------------------------------
// K0: At[j][i] = sum_e Wq[e][i] * Wk[e][j]   (i.e. (Wq^T Wk) stored transposed)
// ---------------------------------------------------------------------------
__global__ __launch_bounds__(256) void at_kernel(const float* __restrict__ Wq,
                                                 const float* __restrict__ Wk,
                                                 float* __restrict__ At){
  const int i0 = blockIdx.x * 32, j0 = blockIdx.y * 32;
  __shared__ float q_s[32][33];
  __shared__ float k_s[32][33];
  const int t = threadIdx.x;
  const int tx = t & 15, ty = t >> 4;
  float acc[2][2] = {{0.f,0.f},{0.f,0.f}};
  for (int e0 = 0; e0 < DD; e0 += 32){
    __syncthreads();
#pragma unroll
    for (int p = 0; p < 4; ++p){
      int idx = t + 256*p;
      int e = idx >> 5, c = idx & 31;
      q_s[e][c] = Wq[(size_t)(e0+e)*DD + i0 + c];
      k_s[e][c] = Wk[(size_t)(e0+e)*DD + j0 + c];
    }
    __syncthreads();
#pragma unroll 8
    for (int e = 0; e < 32; ++e){
      float q0 = q_s[e][2*tx], q1 = q_s[e][2*tx+1];
      float k0 = k_s[e][2*ty], k1 = k_s[e][2*ty+1];
      acc[0][0] += k0*q0; acc[0][1] += k0*q1;
      acc[1][0] += k1*q0; acc[1][1] += k1*q1;
    }
  }
#pragma unroll
  for (int a = 0; a < 2; ++a)
#pragma unroll
    for (int b = 0; b < 2; ++b)
      At[(size_t)(j0 + 2*ty + a)*DD + i0 + 2*tx + b] = acc[a][b];
}

// c2[d] = sum_e bq[e] * Wk[e][d]
__global__ __launch_bounds__(256) void c2_kernel(const float* __restrict__ bq,
                                                 const float* __restrict__ Wk,
                                                 float* __restrict__ c2){
  int d = blockIdx.x * 256 + threadIdx.x;
  float a = 0.f;
  for (int e = 0; e < DD; ++e) a += bq[e] * Wk[(size_t)e*DD + d];
  c2[d] = a;
}

// s[b*M+m] = dot(camera[b,m,:], c2)
__global__ __launch_bounds__(64) void s_kernel(const float* __restrict__ cam,
                                               const float* __restrict__ c2,
                                               float* __restrict__ svec){
  size_t row = blockIdx.x;
  const float* y = cam + row * DD;
  int l = threadIdx.x;
  float a = 0.f;
#pragma unroll
  for (int i = 0; i < 8; ++i) a += y[l + 64*i] * c2[l + 64*i];
  for (int o = 32; o; o >>= 1) a += __shfl_xor(a, o);
  if (l == 0) svec[row] = a;
}

// ---------------------------------------------------------------------------
// BT-form GEMM: O[row,col] = sum_k A[row,k]*B[col,k]  (both row-major, K contiguous)
// 128x128 tile, BK=32, 4 waves each 64x64 (4x4 fragments of 16x16x32 MFMA).
// X3: both operands split hi/lo bf16, acc = hh + hl + lh  (~f32 precision).
// MODE 0: f32 out.  MODE 1: bf16 out + bias[row].  MODE 2: f32 out,
//   conf[bz*NN+row]*(acc + svec[bz*MM+col]).  MODE 3 == 0.
// ---------------------------------------------------------------------------
template<int MODE, bool SRC_BF16, bool X3>
__global__ __launch_bounds__(256) void gemm_bt(
    const void* __restrict__ Ain, long sA, int lda,
    const void* __restrict__ Bin, long sB, int ldb,
    void* __restrict__ Oin, long sO, int ldo, int K,
    const float* __restrict__ bias,
    const float* __restrict__ conf,
    const float* __restrict__ svec)
{
  __shared__ __attribute__((aligned(16))) unsigned short Ah[128][40];
  __shared__ __attribute__((aligned(16))) unsigned short Bh[128][40];
  __shared__ __attribute__((aligned(16))) unsigned short Al[X3?128:1][40];
  __shared__ __attribute__((aligned(16))) unsigned short Bl[X3?128:1][40];

  const int t = threadIdx.x;
  const int bn = blockIdx.x, bm = blockIdx.y, bz = blockIdx.z;
  const int lane = t & 63;
  const int w = t >> 6;
  const int wrow = w >> 1, wcol = w & 1;
  const int lr = lane & 15, lk = (lane >> 4) << 3;

  f32x4 acc[4][4];
#pragma unroll
  for (int m = 0; m < 4; ++m)
#pragma unroll
    for (int n = 0; n < 4; ++n){ f32x4 z = {0.f,0.f,0.f,0.f}; acc[m][n] = z; }

  for (int k0 = 0; k0 < K; k0 += 32){
    __syncthreads();
    if constexpr (!SRC_BF16){
      const float* Ap = (const float*)Ain + (size_t)bz*(size_t)sA + ((size_t)bm*128)*(size_t)lda + k0;
      const float* Bp = (const float*)Bin + (size_t)bz*(size_t)sB + ((size_t)bn*128)*(size_t)ldb + k0;
#pragma unroll
      for (int p = 0; p < 4; ++p){
        int r = (t >> 3) + 32*p;
        int c = (t & 7) * 4;
        float4 va = *(const float4*)(Ap + (size_t)r*lda + c);
        float4 vb = *(const float4*)(Bp + (size_t)r*ldb + c);
        ushort4 ha; ha.x=f2bf(va.x); ha.y=f2bf(va.y); ha.z=f2bf(va.z); ha.w=f2bf(va.w);
        ushort4 hb; hb.x=f2bf(vb.x); hb.y=f2bf(vb.y); hb.z=f2bf(vb.z); hb.w=f2bf(vb.w);
        *(ushort4*)&Ah[r][c] = ha;
        *(ushort4*)&Bh[r][c] = hb;
        if constexpr (X3){
          ushort4 la; la.x=f2bf(va.x-bf2f(ha.x)); la.y=f2bf(va.y-bf2f(ha.y));
                      la.z=f2bf(va.z-bf2f(ha.z)); la.w=f2bf(va.w-bf2f(ha.w));
          ushort4 lb; lb.x=f2bf(vb.x-bf2f(hb.x)); lb.y=f2bf(vb.y-bf2f(hb.y));
                      lb.z=f2bf(vb.z-bf2f(hb.z)); lb.w=f2bf(vb.w-bf2f(hb.w));
          *(ushort4*)&Al[r][c] = la;
          *(ushort4*)&Bl[r][c] = lb;
        }
      }
    } else {
      const unsigned short* Ap = (const unsigned short*)Ain + (size_t)bz*(size_t)sA + ((size_t)bm*128)*(size_t)lda + k0;
      const unsigned short* Bp = (const unsigned short*)Bin + (size_t)bz*(size_t)sB + ((size_t)bn*128)*(size_t)ldb + k0;
#pragma unroll
      for (int p = 0; p < 2; ++p){
        int r = (t >> 2) + 64*p;
        int c = (t & 3) * 8;
        *(u16x8*)&Ah[r][c] = *(const u16x8*)(Ap + (size_t)r*lda + c);
        *(u16x8*)&Bh[r][c] = *(const u16x8*)(Bp + (size_t)r*ldb + c);
      }
    }
    __syncthreads();

    bf16x8 ah[4], bh[4];
#pragma unroll
    for (int m = 0; m < 4; ++m) ah[m] = *(const bf16x8*)&Ah[wrow*64 + m*16 + lr][lk];
#pragma unroll
    for (int n = 0; n < 4; ++n) bh[n] = *(const bf16x8*)&Bh[wcol*64 + n*16 + lr][lk];
    if constexpr (X3){
      bf16x8 al[4], bl[4];
#pragma unroll
      for (int m = 0; m < 4; ++m) al[m] = *(const bf16x8*)&Al[wrow*64 + m*16 + lr][lk];
#pragma unroll
      for (int n = 0; n < 4; ++n) bl[n] = *(const bf16x8*)&Bl[wcol*64 + n*16 + lr][lk];
#pragma unroll
      for (int m = 0; m < 4; ++m)
#pragma unroll
        for (int n = 0; n < 4; ++n){
          acc[m][n] = mfma16(ah[m], bh[n], acc[m][n]);
          acc[m][n] = mfma16(ah[m], bl[n], acc[m][n]);
          acc[m][n] = mfma16(al[m], bh[n], acc[m][n]);
        }
    } else {
#pragma unroll
      for (int m = 0; m < 4; ++m)
#pragma unroll
        for (int n = 0; n < 4; ++n)
          acc[m][n] = mfma16(ah[m], bh[n], acc[m][n]);
    }
  }

  const int orow = bm*128 + wrow*64;
  const int ocol = bn*128 + wcol*64;
#pragma unroll
  for (int m = 0; m < 4; ++m){
#pragma unroll
    for (int n = 0; n < 4; ++n){
      int col  = ocol + n*16 + lr;
      int row0 = orow + m*16 + ((lane >> 4) << 2);
#pragma unroll
      for (int r = 0; r < 4; ++r){
        int row = row0 + r;
        float v = acc[m][n][r];
        if constexpr (MODE == 1){
          unsigned short* O = (unsigned short*)Oin + (size_t)bz*(size_t)sO;
          O[(size_t)row*ldo + col] = f2bf(v + bias[row]);
        } else if constexpr (MODE == 2){
          float* O = (float*)Oin + (size_t)bz*(size_t)sO;
          O[(size_t)row*ldo + col] = conf[bz*NN + row] * (v + svec[bz*MM + col]);
        } else {
          float* O = (float*)Oin + (size_t)bz*(size_t)sO;
          O[(size_t)row*ldo + col] = v;
        }
      }
    }
  }
}

// ---------------------------------------------------------------------------
// Row softmax over M=2048, f32 in, bf16 out written in-place into the row's
// own 8KB slot (first 4KB).  One 256-thread block per row.
// ---------------------------------------------------------------------------
__global__ __launch_bounds__(256) void softmax_kernel(float* __restrict__ scores){
  const size_t row = blockIdx.x;
  float* src = scores + row * MM;
  unsigned short* dst = (unsigned short*)scores + row * (size_t)(2*MM);
  const int t = threadIdx.x;

  float4 v0 = ((const float4*)src)[t];
  float4 v1 = ((const float4*)src)[t + 256];

  float mx = fmaxf(fmaxf(fmaxf(v0.x,v0.y), fmaxf(v0.z,v0.w)),
                   fmaxf(fmaxf(v1.x,v1.y), fmaxf(v1.z,v1.w)));
  for (int o = 32; o; o >>= 1) mx = fmaxf(mx, __shfl_xor(mx, o));
  __shared__ float red[4];
  if ((t & 63) == 0) red[t >> 6] = mx;
  __syncthreads();
  mx = fmaxf(fmaxf(red[0], red[1]), fmaxf(red[2], red[3]));

  float e0x = __expf(v0.x - mx), e0y = __expf(v0.y - mx);
  float e0z = __expf(v0.z - mx), e0w = __expf(v0.w - mx);
  float e1x = __expf(v1.x - mx), e1y = __expf(v1.y - mx);
  float e1z = __expf(v1.z - mx), e1w = __expf(v1.w - mx);
  float s = e0x+e0y+e0z+e0w+e1x+e1y+e1z+e1w;
  for (int o = 32; o; o >>= 1) s += __shfl_xor(s, o);
  __syncthreads();               // everyone done reading red[] (max phase)
  if ((t & 63) == 0) red[t >> 6] = s;
  __syncthreads();
  float inv = 1.f / (red[0] + red[1] + red[2] + red[3]);

  ushort4 p0; p0.x=f2bf(e0x*inv); p0.y=f2bf(e0y*inv); p0.z=f2bf(e0z*inv); p0.w=f2bf(e0w*inv);
  ushort4 p1; p1.x=f2bf(e1x*inv); p1.y=f2bf(e1y*inv); p1.z=f2bf(e1z*inv); p1.w=f2bf(e1w*inv);
  ((ushort4*)dst)[t]       = p0;
  ((ushort4*)dst)[t + 256] = p1;
}

// ---------------------------------------------------------------------------
extern "C" void kernel_launch(void* const* d_in, const int* in_sizes, int n_in,
                              void* d_out, int out_size, void* d_ws, size_t ws_size,
                              hipStream_t stream) {
  const float* lidar  = (const float*)d_in[0];   // [B,N,D]
  const float* camera = (const float*)d_in[1];   // [B,M,D]
  const float* lconf  = (const float*)d_in[2];   // [B,N,1]
  // d_in[3] camera_confidence: unused by the reference
  const float* Wq = (const float*)d_in[4];
  const float* bq = (const float*)d_in[5];
  const float* Wk = (const float*)d_in[6];
  // d_in[7] bk: contributes only a per-row constant to scores -> softmax-invariant
  const float* Wv = (const float*)d_in[8];
  const float* bv = (const float*)d_in[9];
  float* out = (float*)d_out;                    // [B,N,D] f32

  // workspace layout (bytes); total 185,665,536 (~178 MB)
  char* ws = (char*)d_ws;
  float*          T      = (float*)(ws + 0);                 // [B,N,D] f32   33.5MB
  float*          scores = (float*)(ws + 33554432);          // [B,N,M] f32  134.2MB (P bf16 aliased in-place)
  unsigned short* Vt     = (unsigned short*)(ws + 167772160);// [B,D,M] bf16  16.8MB
  float*          At     = (float*)(ws + 184549376);         // [D,D]  f32     1MB
  float*          c2     = (float*)(ws + 185597952);         // [D]
  float*          svec   = (float*)(ws + 185600000);         // [B,M]

  // K0: At = (Wq^T Wk)^T, c2 = bq @ Wk
  at_kernel<<<dim3(16,16), 256, 0, stream>>>(Wq, Wk, At);
  c2_kernel<<<dim3(2), 256, 0, stream>>>(bq, Wk, c2);
  // s[b,m] = camera[b,m,:] . c2
  s_kernel<<<dim3(BB*MM), 64, 0, stream>>>(camera, c2, svec);

  // T = lidar @ At^T   (x3 precision), M=2048 N=512 K=512
  gemm_bt<0,false,true><<<dim3(DD/128, NN/128, BB), 256, 0, stream>>>(
      lidar, (long)NN*DD, DD,  At, 0, DD,
      T, (long)NN*DD, DD, DD, nullptr, nullptr, nullptr);

  // Vt[e,m] = Wv[e,:] . camera[m,:] + bv[e]   (plain bf16), M=512 N=2048 K=512
  gemm_bt<1,false,false><<<dim3(MM/128, DD/128, BB), 256, 0, stream>>>(
      Wv, 0, DD,  camera, (long)MM*DD, DD,
      Vt, (long)DD*MM, MM, DD, bv, nullptr, nullptr);

  // scores = conf * (T @ camera^T + s)   (x3), M=2048 N=2048 K=512
  gemm_bt<2,false,true><<<dim3(MM/128, NN/128, BB), 256, 0, stream>>>(
      T, (long)NN*DD, DD,  camera, (long)MM*DD, DD,
      scores, (long)NN*MM, MM, DD, nullptr, lconf, svec);

  // row softmax, P bf16 in-place (row stride 2*MM bf16 elems)
  softmax_kernel<<<dim3(BB*NN), 256, 0, stream>>>(scores);

  // out = P @ Vt^T   (plain bf16 inputs), M=2048 N=512 K=2048
  gemm_bt<3,true,false><<<dim3(DD/128, NN/128, BB), 256, 0, stream>>>(
      (const unsigned short*)scores, (long)NN*2*MM, 2*MM,
      Vt, (long)DD*MM, MM,
      out, (long)NN*DD, DD, MM, nullptr, nullptr, nullptr);
}